// Round 4
// baseline (570.119 us; speedup 1.0000x reference)
//
#include <hip/hip_runtime.h>

#define NN 50000
#define EE 800000
#define FIN 128
#define HH 256
#define NL 3

#define BM 64
#define BK 32

typedef __bf16 bf16x8 __attribute__((ext_vector_type(8)));
typedef float  f32x4  __attribute__((ext_vector_type(4)));
typedef unsigned short u16x8 __attribute__((ext_vector_type(8)));

__device__ __forceinline__ float bf2f(unsigned short u){
    union { unsigned int i; float f; } v; v.i = ((unsigned int)u) << 16; return v.f;
}
__device__ __forceinline__ unsigned short f2bf(float f){
    union { float f; unsigned int i; } v; v.f = f;
    unsigned int r = v.i + 0x7FFF + ((v.i >> 16) & 1);  // RNE
    return (unsigned short)(r >> 16);
}
__device__ __forceinline__ void gload16(const void* g, void* s){
    __builtin_amdgcn_global_load_lds(
        (const __attribute__((address_space(1))) void*)g,
        (__attribute__((address_space(3))) void*)s, 16, 0, 0);
}
#define WAITV4 asm volatile("s_waitcnt vmcnt(4)" ::: "memory")
#define WAITV5 asm volatile("s_waitcnt vmcnt(5)" ::: "memory")
#define WAITV0 asm volatile("s_waitcnt vmcnt(0)" ::: "memory")

// ---------------- CSR build ----------------
__global__ void k_zero_i32(int* __restrict__ p, int n){
    int i = blockIdx.x*256 + threadIdx.x;
    if (i < n) p[i] = 0;
}
__global__ void k_count_deg(const int* __restrict__ dst, int* __restrict__ deg){
    int i = blockIdx.x*256 + threadIdx.x;
    if (i < EE) atomicAdd(&deg[dst[i]], 1);
}
__global__ void k_block_sum(const int* __restrict__ deg, int* __restrict__ bsum){
    __shared__ int s[1024];
    int i = blockIdx.x*1024 + threadIdx.x;
    s[threadIdx.x] = (i < NN) ? deg[i] : 0;
    __syncthreads();
    for (int o = 512; o > 0; o >>= 1){
        if (threadIdx.x < o) s[threadIdx.x] += s[threadIdx.x + o];
        __syncthreads();
    }
    if (threadIdx.x == 0) bsum[blockIdx.x] = s[0];
}
__global__ void k_scan_bsum(int* __restrict__ bsum, int nb){
    if (threadIdx.x == 0 && blockIdx.x == 0){
        int run = 0;
        for (int i = 0; i < nb; ++i){ int v = bsum[i]; bsum[i] = run; run += v; }
    }
}
__global__ void k_make_off(const int* __restrict__ deg, const int* __restrict__ bsum,
                           int* __restrict__ off, int* __restrict__ pos,
                           float* __restrict__ invd){
    __shared__ int s[1024];
    int t = threadIdx.x;
    int i = blockIdx.x*1024 + t;
    int v = (i < NN) ? deg[i] : 0;
    s[t] = v; __syncthreads();
    for (int o = 1; o < 1024; o <<= 1){
        int add = (t >= o) ? s[t - o] : 0;
        __syncthreads();
        s[t] += add;
        __syncthreads();
    }
    if (i < NN){
        int excl = s[t] - v + bsum[blockIdx.x];
        off[i] = excl; pos[i] = excl;
        invd[i] = 1.0f / fmaxf((float)v, 1.0f);
    }
}
__global__ void k_build_csr(const int* __restrict__ src, const int* __restrict__ dst,
                            int* __restrict__ pos, int* __restrict__ csr){
    int i = blockIdx.x*256 + threadIdx.x;
    if (i < EE){
        int p = atomicAdd(&pos[dst[i]], 1);
        csr[p] = src[i];
    }
}

// ---------------- casts ----------------
__global__ void k_cast4(const float* __restrict__ in, unsigned short* __restrict__ ob, int n4){
    int i = blockIdx.x*256 + threadIdx.x;
    if (i < n4){
        float4 v = *(const float4*)&in[i*4];
        ushort4 o; o.x=f2bf(v.x); o.y=f2bf(v.y); o.z=f2bf(v.z); o.w=f2bf(v.w);
        *(ushort4*)&ob[i*4] = o;
    }
}
__global__ void k_cast_wcat(const float* __restrict__ Wl, const float* __restrict__ Wr,
                            unsigned short* __restrict__ Wb){
    int i = blockIdx.x*256 + threadIdx.x;   // [l][n][k], k in [0,512)
    if (i < NL*HH*2*HH){
        int k = i & 511; int n = (i >> 9) & 255; int lyr = i >> 17;
        float v = (k < HH) ? Wl[((size_t)(lyr*HH)+n)*HH + k]
                           : Wr[((size_t)(lyr*HH)+n)*HH + (k-HH)];
        Wb[i] = f2bf(v);
    }
}

// ============ fused MFMA GEMM, BM=64 x BN=256, optional in-block aggregation ============
// FUSE=0: A streamed from A0 (proj).   FUSE=1: k<K0 half of A = mean-aggregated
// neighbor rows of hb, gathered by this block into LDS; k>=K0 half = A1 streamed.
// EPI 0: outb = bf16(relu(C+bias));  EPI 1: outb = bf16(relu(LN(C+bias))+resb);
// EPI 2: outf = relu(LN(C+bias))+resb.
template<int EPI, int FUSE>
__global__ __launch_bounds__(256) void k_gemm_mfma(
    const unsigned short* __restrict__ A0, int lda0,
    const unsigned short* __restrict__ A1, int lda1,
    const unsigned short* __restrict__ Bt,
    const float* __restrict__ bias,
    const float* __restrict__ gamma, const float* __restrict__ beta,
    const unsigned short* __restrict__ resb,
    float* __restrict__ outf, unsigned short* __restrict__ outb,
    const unsigned short* __restrict__ hb, const int* __restrict__ csr,
    const int* __restrict__ offs, const int* __restrict__ deg,
    const float* __restrict__ invd,
    int K0, int KTOT)
{
    constexpr int A0SZ  = FUSE ? 32768 : 0;     // 8 chunks x [64 rows][64B], swizzled
    constexpr int BOFF  = A0SZ;                 // B double-buffer: 2 x 16 KB
    constexpr int A1OFF = A0SZ + 2*16384;       // A-stream double-buffer: 2 x 4 KB
    __shared__ char smem[A1OFF + 2*4096];       // FUSE: 72 KB, else 40 KB
    const int t  = threadIdx.x;
    const int w  = t >> 6, l = t & 63;
    const int lr = l & 15, lg = l >> 4;
    const int m0 = blockIdx.x * BM;

    // ---- staging address setup (global src pre-swizzled; LDS dest linear: rule #21) ----
    const int pA   = w*1024 + l*16;
    const int rowA = pA >> 6;
    const int swzA = (pA & 63) ^ ((rowA & 6) << 3);
    int growA = m0 + rowA; if (growA > NN-1) growA = NN-1;
    const char* a0base = (const char*)(A0 + (size_t)growA*lda0) + swzA;
    const char* a1base = (const char*)(A1 + (size_t)growA*lda1) + swzA;
    const char* bbase[4];
    #pragma unroll
    for (int c = 0; c < 4; ++c){
        int p = (w*4 + c)*1024 + l*16;
        int n = p >> 6;
        int swz = (p & 63) ^ ((n & 6) << 3);
        bbase[c] = (const char*)(Bt + (size_t)n*KTOT) + swz;
    }

    f32x4 acc[4][4] = {};

    auto stage = [&](int s, int buf){
        const int k0 = s * BK;
        #pragma unroll
        for (int c = 0; c < 4; ++c)
            gload16(bbase[c] + (size_t)k0*2, smem + BOFF + buf*16384 + (w*4 + c)*1024);
        if (!FUSE)
            gload16(a0base + (size_t)k0*2, smem + A1OFF + buf*4096 + w*1024);
        else if (k0 >= K0)
            gload16(a1base + (size_t)(k0 - K0)*2, smem + A1OFF + buf*4096 + w*1024);
    };

    stage(0, 0);   // B (and A for !FUSE) prefetch; overlaps the gather below

    if (FUSE){
        // ---- in-block aggregation: wave w owns rows w*16..w*16+15 ----
        const int half = l >> 5;     // neighbor parity
        const int fl   = l & 31;     // 16B feature slot (8 bf16)
        for (int i = 0; i < 16; ++i){
            int r = w*16 + i;
            int node = m0 + r; if (node > NN-1) node = NN-1;
            int o = offs[node], d = deg[node];
            float a8[8] = {};
            int j = 0;
            for (; j + 8 <= d; j += 8){
                int s0 = csr[o + j     + half];
                int s1 = csr[o + j + 2 + half];
                int s2 = csr[o + j + 4 + half];
                int s3 = csr[o + j + 6 + half];
                u16x8 v0 = *(const u16x8*)&hb[(size_t)s0*HH + fl*8];
                u16x8 v1 = *(const u16x8*)&hb[(size_t)s1*HH + fl*8];
                u16x8 v2 = *(const u16x8*)&hb[(size_t)s2*HH + fl*8];
                u16x8 v3 = *(const u16x8*)&hb[(size_t)s3*HH + fl*8];
                #pragma unroll
                for (int k = 0; k < 8; ++k)
                    a8[k] += (bf2f(v0[k]) + bf2f(v1[k])) + (bf2f(v2[k]) + bf2f(v3[k]));
            }
            for (; j < d; j += 2){
                int idx = j + half;
                if (idx < d){
                    int s0 = csr[o + idx];
                    u16x8 v0 = *(const u16x8*)&hb[(size_t)s0*HH + fl*8];
                    #pragma unroll
                    for (int k = 0; k < 8; ++k) a8[k] += bf2f(v0[k]);
                }
            }
            #pragma unroll
            for (int k = 0; k < 8; ++k) a8[k] += __shfl_xor(a8[k], 32);
            if (half == 0){
                float id = invd[node];
                u16x8 rr;
                #pragma unroll
                for (int k = 0; k < 8; ++k) rr[k] = f2bf(a8[k]*id);
                int ks = fl >> 2, q = fl & 3;
                *(u16x8*)(smem + ks*4096 + r*64 + ((q*16) ^ ((r & 6) << 3))) = rr;
            }
        }
        __syncthreads();   // drain ds_writes; A0 region valid for all waves
    }

    const int nsteps = KTOT / BK;
    for (int s = 0; s < nsteps; ++s){
        const int cur = s & 1;
        if (s + 1 < nsteps){
            stage(s + 1, cur ^ 1);
            if (FUSE && (s + 1)*BK < K0) { WAITV4; } else { WAITV5; }
        } else {
            WAITV0;
        }
        __builtin_amdgcn_s_barrier();
        __builtin_amdgcn_sched_barrier(0);

        const char* As = (FUSE && s*BK < K0) ? (smem + s*4096)
                                             : (smem + A1OFF + cur*4096);
        const char* Bs = smem + BOFF + cur*16384;
        const int kb = lg * 16;
        const int sw = (lr & 6) << 3;
        bf16x8 af[4], bfr[4];
        #pragma unroll
        for (int m = 0; m < 4; ++m){
            int r = m*16 + lr;
            af[m] = *(const bf16x8*)(As + r*64 + (kb ^ sw));
        }
        #pragma unroll
        for (int n = 0; n < 4; ++n){
            int r = w*64 + n*16 + lr;
            bfr[n] = *(const bf16x8*)(Bs + r*64 + (kb ^ sw));
        }
        #pragma unroll
        for (int m = 0; m < 4; ++m)
            #pragma unroll
            for (int n = 0; n < 4; ++n)
                acc[m][n] = __builtin_amdgcn_mfma_f32_16x16x32_bf16(af[m], bfr[n], acc[m][n], 0, 0, 0);

        asm volatile("s_waitcnt lgkmcnt(0)" ::: "memory");
        __builtin_amdgcn_s_barrier();
    }

    // ---- epilogue: C/D layout col=lane&15, row=(lane>>4)*4+reg [m89-verified] ----
    float bcol[4], gcol[4], becol[4];
    #pragma unroll
    for (int n = 0; n < 4; ++n){
        int c = w*64 + n*16 + lr;
        bcol[n] = bias[c];
        if (EPI >= 1){ gcol[n] = gamma[c]; becol[n] = beta[c]; }
    }

    if (EPI == 0){
        #pragma unroll
        for (int m = 0; m < 4; ++m)
        #pragma unroll
        for (int reg = 0; reg < 4; ++reg){
            int R = m*16 + lg*4 + reg;
            int grow = m0 + R;
            if (grow >= NN) continue;
            #pragma unroll
            for (int n = 0; n < 4; ++n){
                int c = w*64 + n*16 + lr;
                float v = fmaxf(acc[m][n][reg] + bcol[n], 0.f);
                outb[(size_t)grow*HH + c] = f2bf(v);
            }
        }
    } else {
        float sm[4][4], sq[4][4];
        #pragma unroll
        for (int m = 0; m < 4; ++m)
        #pragma unroll
        for (int reg = 0; reg < 4; ++reg){
            float s = 0.f, q = 0.f;
            #pragma unroll
            for (int n = 0; n < 4; ++n){
                float v = acc[m][n][reg] + bcol[n];
                acc[m][n][reg] = v;
                s += v; q += v*v;
            }
            sm[m][reg] = s; sq[m][reg] = q;
        }
        #pragma unroll
        for (int mask = 1; mask <= 8; mask <<= 1){
            #pragma unroll
            for (int m = 0; m < 4; ++m)
            #pragma unroll
            for (int reg = 0; reg < 4; ++reg){
                sm[m][reg] += __shfl_xor(sm[m][reg], mask);
                sq[m][reg] += __shfl_xor(sq[m][reg], mask);
            }
        }
        float* red = (float*)smem;   // A0/B regions dead after last K-step barrier
        __syncthreads();
        if (lr == 0){
            #pragma unroll
            for (int m = 0; m < 4; ++m)
            #pragma unroll
            for (int reg = 0; reg < 4; ++reg){
                int R = m*16 + lg*4 + reg;
                red[(w*64 + R)*2 + 0] = sm[m][reg];
                red[(w*64 + R)*2 + 1] = sq[m][reg];
            }
        }
        __syncthreads();
        #pragma unroll
        for (int m = 0; m < 4; ++m)
        #pragma unroll
        for (int reg = 0; reg < 4; ++reg){
            int R = m*16 + lg*4 + reg;
            float S = 0.f, Q = 0.f;
            #pragma unroll
            for (int ww = 0; ww < 4; ++ww){
                S += red[(ww*64 + R)*2 + 0];
                Q += red[(ww*64 + R)*2 + 1];
            }
            float mean = S * (1.0f/HH);
            float var  = Q * (1.0f/HH) - mean*mean;
            float inv  = rsqrtf(var + 1e-5f);
            int grow = m0 + R;
            if (grow >= NN) continue;
            #pragma unroll
            for (int n = 0; n < 4; ++n){
                int c = w*64 + n*16 + lr;
                float o = fmaxf((acc[m][n][reg] - mean)*inv*gcol[n] + becol[n], 0.f)
                          + bf2f(resb[(size_t)grow*HH + c]);
                if (EPI == 1) outb[(size_t)grow*HH + c] = f2bf(o);
                else          outf[(size_t)grow*HH + c] = o;
            }
        }
    }
}

// ---------------- host ----------------
extern "C" void kernel_launch(void* const* d_in, const int* in_sizes, int n_in,
                              void* d_out, int out_size, void* d_ws, size_t ws_size,
                              hipStream_t stream) {
    const float* x     = (const float*)d_in[0];
    const int*   ei    = (const int*)d_in[1];
    const int*   srcI  = ei;
    const int*   dstI  = ei + EE;
    const float* Wp    = (const float*)d_in[2];
    const float* bp    = (const float*)d_in[3];
    const float* Wl    = (const float*)d_in[4];
    const float* bl    = (const float*)d_in[5];
    const float* Wr    = (const float*)d_in[6];
    const float* gamma = (const float*)d_in[7];
    const float* beta  = (const float*)d_in[8];
    float* out = (float*)d_out;

    char* ws = (char*)d_ws;
    size_t off_b = 0;
    auto alloc = [&](size_t bytes) -> char* {
        char* p = ws + off_b;
        off_b = (off_b + bytes + 255) & ~(size_t)255;
        return p;
    };
    unsigned short* Hb0 = (unsigned short*)alloc((size_t)NN*HH*2);
    unsigned short* Hb1 = (unsigned short*)alloc((size_t)NN*HH*2);
    unsigned short* Xb  = (unsigned short*)alloc((size_t)NN*FIN*2);
    int*   csr  = (int*)alloc((size_t)EE*4);
    int*   deg  = (int*)alloc((size_t)NN*4);
    int*   offs = (int*)alloc((size_t)NN*4);
    int*   pos  = (int*)alloc((size_t)NN*4);
    float* invd = (float*)alloc((size_t)NN*4);
    int*   bsum = (int*)alloc(64*4);
    unsigned short* Wpb = (unsigned short*)alloc((size_t)HH*FIN*2);
    unsigned short* Wb  = (unsigned short*)alloc((size_t)NL*HH*2*HH*2);
    (void)ws_size; (void)in_sizes; (void)n_in; (void)out_size;

    const int NB = (NN + 1023)/1024;

    k_zero_i32<<<(NN + 255)/256, 256, 0, stream>>>(deg, NN);
    k_count_deg<<<(EE + 255)/256, 256, 0, stream>>>(dstI, deg);
    k_block_sum<<<NB, 1024, 0, stream>>>(deg, bsum);
    k_scan_bsum<<<1, 1, 0, stream>>>(bsum, NB);
    k_make_off<<<NB, 1024, 0, stream>>>(deg, bsum, offs, pos, invd);
    k_build_csr<<<(EE + 255)/256, 256, 0, stream>>>(srcI, dstI, pos, csr);

    k_cast4<<<(NN*FIN/4 + 255)/256, 256, 0, stream>>>(x, Xb, NN*FIN/4);
    k_cast4<<<(HH*FIN/4 + 255)/256, 256, 0, stream>>>(Wp, Wpb, HH*FIN/4);
    k_cast_wcat<<<(NL*HH*2*HH + 255)/256, 256, 0, stream>>>(Wl, Wr, Wb);

    const int GB = (NN + BM - 1)/BM;  // 782

    // input projection + ReLU -> Hb0 (bf16)
    k_gemm_mfma<0,0><<<GB, 256, 0, stream>>>(Xb, FIN, Xb, FIN, Wpb, bp,
                                             nullptr, nullptr, nullptr,
                                             nullptr, Hb0,
                                             nullptr, nullptr, nullptr, nullptr, nullptr,
                                             FIN, FIN);

    unsigned short* hin = Hb0;
    for (int lyr = 0; lyr < NL; ++lyr){
        unsigned short* hout = (hin == Hb0) ? Hb1 : Hb0;
        const unsigned short* Wbt = Wb + (size_t)lyr*HH*2*HH;
        if (lyr < NL-1)
            k_gemm_mfma<1,1><<<GB, 256, 0, stream>>>(hin, HH, hin, HH, Wbt, bl + lyr*HH,
                                                     gamma + lyr*HH, beta + lyr*HH, hin,
                                                     nullptr, hout,
                                                     hin, csr, offs, deg, invd,
                                                     HH, 2*HH);
        else
            k_gemm_mfma<2,1><<<GB, 256, 0, stream>>>(hin, HH, hin, HH, Wbt, bl + lyr*HH,
                                                     gamma + lyr*HH, beta + lyr*HH, hin,
                                                     out, nullptr,
                                                     hin, csr, offs, deg, invd,
                                                     HH, 2*HH);
        hin = hout;
    }
}

// Round 5
// 404.276 us; speedup vs baseline: 1.4102x; 1.4102x over previous
//
#include <hip/hip_runtime.h>

#define NN 50000
#define EE 800000
#define FIN 128
#define HH 256
#define NL 3

#define BM 64
#define BK 32
#define ABYTES (BM*BK*2)          // 4096
#define BBYTES (HH*BK*2)          // 16384
#define TILEB  (ABYTES + BBYTES)  // 20480

typedef __bf16 bf16x8 __attribute__((ext_vector_type(8)));
typedef float  f32x4  __attribute__((ext_vector_type(4)));
typedef unsigned short u16x8 __attribute__((ext_vector_type(8)));

__device__ __forceinline__ float bf2f(unsigned short u){
    union { unsigned int i; float f; } v; v.i = ((unsigned int)u) << 16; return v.f;
}
__device__ __forceinline__ unsigned short f2bf(float f){
    union { float f; unsigned int i; } v; v.f = f;
    unsigned int r = v.i + 0x7FFF + ((v.i >> 16) & 1);  // RNE
    return (unsigned short)(r >> 16);
}
__device__ __forceinline__ void gload16(const void* g, void* s){
    __builtin_amdgcn_global_load_lds(
        (const __attribute__((address_space(1))) void*)g,
        (__attribute__((address_space(3))) void*)s, 16, 0, 0);
}

// ---------------- CSR build ----------------
__global__ void k_zero_i32(int* __restrict__ p, int n){
    int i = blockIdx.x*256 + threadIdx.x;
    if (i < n) p[i] = 0;
}
__global__ void k_count_deg(const int* __restrict__ dst, int* __restrict__ deg){
    int i = blockIdx.x*256 + threadIdx.x;
    if (i < EE) atomicAdd(&deg[dst[i]], 1);
}
__global__ void k_block_sum(const int* __restrict__ deg, int* __restrict__ bsum){
    __shared__ int s[1024];
    int i = blockIdx.x*1024 + threadIdx.x;
    s[threadIdx.x] = (i < NN) ? deg[i] : 0;
    __syncthreads();
    for (int o = 512; o > 0; o >>= 1){
        if (threadIdx.x < o) s[threadIdx.x] += s[threadIdx.x + o];
        __syncthreads();
    }
    if (threadIdx.x == 0) bsum[blockIdx.x] = s[0];
}
__global__ void k_scan_bsum(int* __restrict__ bsum, int nb){
    if (threadIdx.x == 0 && blockIdx.x == 0){
        int run = 0;
        for (int i = 0; i < nb; ++i){ int v = bsum[i]; bsum[i] = run; run += v; }
    }
}
__global__ void k_make_off(const int* __restrict__ deg, const int* __restrict__ bsum,
                           int* __restrict__ off, int* __restrict__ pos,
                           float* __restrict__ invd){
    __shared__ int s[1024];
    int t = threadIdx.x;
    int i = blockIdx.x*1024 + t;
    int v = (i < NN) ? deg[i] : 0;
    s[t] = v; __syncthreads();
    for (int o = 1; o < 1024; o <<= 1){
        int add = (t >= o) ? s[t - o] : 0;
        __syncthreads();
        s[t] += add;
        __syncthreads();
    }
    if (i < NN){
        int excl = s[t] - v + bsum[blockIdx.x];
        off[i] = excl; pos[i] = excl;
        invd[i] = 1.0f / fmaxf((float)v, 1.0f);
    }
}
__global__ void k_build_csr(const int* __restrict__ src, const int* __restrict__ dst,
                            int* __restrict__ pos, int* __restrict__ csr){
    int i = blockIdx.x*256 + threadIdx.x;
    if (i < EE){
        int p = atomicAdd(&pos[dst[i]], 1);
        csr[p] = src[i];
    }
}

// ---------------- fused prep: cast x, Wp, and [Wl|Wr] concat to bf16 ----------------
#define NX  (NN*FIN/4)        // x, 4-wide
#define NWP (HH*FIN/4)        // Wp, 4-wide
#define NWC (NL*HH*2*HH/4)    // Wcat, 4-wide
__global__ void k_prep(const float* __restrict__ x, const float* __restrict__ Wp,
                       const float* __restrict__ Wl, const float* __restrict__ Wr,
                       unsigned short* __restrict__ Xb, unsigned short* __restrict__ Wpb,
                       unsigned short* __restrict__ Wb){
    int i = blockIdx.x*256 + threadIdx.x;
    if (i < NX){
        float4 v = *(const float4*)&x[i*4];
        ushort4 o; o.x=f2bf(v.x); o.y=f2bf(v.y); o.z=f2bf(v.z); o.w=f2bf(v.w);
        *(ushort4*)&Xb[i*4] = o;
        return;
    }
    int j = i - NX;
    if (j < NWP){
        float4 v = *(const float4*)&Wp[j*4];
        ushort4 o; o.x=f2bf(v.x); o.y=f2bf(v.y); o.z=f2bf(v.z); o.w=f2bf(v.w);
        *(ushort4*)&Wpb[j*4] = o;
        return;
    }
    int k4 = j - NWP;
    if (k4 < NWC){
        int base = k4*4;
        int kk  = base & 511;
        int n   = (base >> 9) & (HH-1);
        int lyr = base >> 17;
        const float* srcp = (kk < HH) ? &Wl[((size_t)lyr*HH + n)*HH + kk]
                                      : &Wr[((size_t)lyr*HH + n)*HH + (kk - HH)];
        float4 v = *(const float4*)srcp;
        ushort4 o; o.x=f2bf(v.x); o.y=f2bf(v.y); o.z=f2bf(v.z); o.w=f2bf(v.w);
        *(ushort4*)&Wb[base] = o;
    }
}

// ---------------- aggregation v3: u8 rows (256B), 16 lanes/row, 4 rows/instr ----------------
__device__ __forceinline__ void accum16(float* a, uint4 v, float c){
    const unsigned int w0 = v.x, w1 = v.y, w2 = v.z, w3 = v.w;
    #pragma unroll
    for (int b = 0; b < 4; ++b){
        a[b]    += c * (float)((w0 >> (8*b)) & 0xFF);
        a[4+b]  += c * (float)((w1 >> (8*b)) & 0xFF);
        a[8+b]  += c * (float)((w2 >> (8*b)) & 0xFF);
        a[12+b] += c * (float)((w3 >> (8*b)) & 0xFF);
    }
}

__global__ __launch_bounds__(256) void k_aggregate_u8(
    const unsigned char* __restrict__ hu, const float* __restrict__ scl,
    const int* __restrict__ csr, const int* __restrict__ off,
    const int* __restrict__ deg, const float* __restrict__ invd,
    unsigned short* __restrict__ aggb)
{
    const int wave = threadIdx.x >> 6, lane = threadIdx.x & 63;
    const int node = blockIdx.x*4 + wave;
    if (node >= NN) return;
    const int o = off[node], d = deg[node];
    const int grp = lane >> 4;    // which neighbor slot (0..3)
    const int fl  = lane & 15;    // 16-byte feature slot

    float acc[16] = {};
    int j = 0;
    for (; j + 16 <= d; j += 16){
        int s0 = csr[o + j      + grp];
        int s1 = csr[o + j + 4  + grp];
        int s2 = csr[o + j + 8  + grp];
        int s3 = csr[o + j + 12 + grp];
        float c0 = scl[s0], c1 = scl[s1], c2 = scl[s2], c3 = scl[s3];
        uint4 v0 = *(const uint4*)&hu[(size_t)s0*HH + fl*16];
        uint4 v1 = *(const uint4*)&hu[(size_t)s1*HH + fl*16];
        uint4 v2 = *(const uint4*)&hu[(size_t)s2*HH + fl*16];
        uint4 v3 = *(const uint4*)&hu[(size_t)s3*HH + fl*16];
        accum16(acc, v0, c0); accum16(acc, v1, c1);
        accum16(acc, v2, c2); accum16(acc, v3, c3);
    }
    for (; j + 8 <= d; j += 8){
        int s0 = csr[o + j     + grp];
        int s1 = csr[o + j + 4 + grp];
        float c0 = scl[s0], c1 = scl[s1];
        uint4 v0 = *(const uint4*)&hu[(size_t)s0*HH + fl*16];
        uint4 v1 = *(const uint4*)&hu[(size_t)s1*HH + fl*16];
        accum16(acc, v0, c0); accum16(acc, v1, c1);
    }
    for (; j < d; j += 4){
        int idx = j + grp;
        int s0 = 0; float c0 = 0.f;
        if (idx < d){ s0 = csr[o + idx]; c0 = scl[s0]; }
        uint4 v0 = *(const uint4*)&hu[(size_t)s0*HH + fl*16];
        accum16(acc, v0, c0);
    }
    #pragma unroll
    for (int k = 0; k < 16; ++k){
        acc[k] += __shfl_xor(acc[k], 16);
        acc[k] += __shfl_xor(acc[k], 32);
    }
    if (grp == 0){
        float id = invd[node];
        u16x8 r0, r1;
        #pragma unroll
        for (int k = 0; k < 8; ++k){
            r0[k] = f2bf(acc[k]*id);
            r1[k] = f2bf(acc[8+k]*id);
        }
        *(u16x8*)&aggb[(size_t)node*HH + fl*16]     = r0;
        *(u16x8*)&aggb[(size_t)node*HH + fl*16 + 8] = r1;
    }
}

// ---------------- MFMA GEMM, BM=64 x BN=256, fused epilogue + u8 quant ----------------
// EPI 0: h = relu(C+bias)            -> outb bf16 + hu u8 + scl
// EPI 1: h = relu(LN(C+bias)) + resb -> outb bf16 + hu u8 + scl
// EPI 2: h = relu(LN(C+bias)) + resb -> outf f32 (final)
template<int EPI>
__global__ __launch_bounds__(256) void k_gemm_mfma(
    const unsigned short* __restrict__ A0, int lda0,
    const unsigned short* __restrict__ A1, int lda1,
    const unsigned short* __restrict__ Bt,
    const float* __restrict__ bias,
    const float* __restrict__ gamma, const float* __restrict__ beta,
    const unsigned short* __restrict__ resb,
    float* __restrict__ outf, unsigned short* __restrict__ outb,
    unsigned char* __restrict__ hu, float* __restrict__ scl,
    int K0, int KTOT)
{
    __shared__ char smem[2*TILEB];   // 40 KB
    const int t  = threadIdx.x;
    const int w  = t >> 6, l = t & 63;
    const int lr = l & 15, lg = l >> 4;
    const int m0 = blockIdx.x * BM;

    // staging (global src pre-swizzled; LDS dest linear: rule #21)
    const int pA   = w*1024 + l*16;
    const int rowA = pA >> 6;
    const int swzA = (pA & 63) ^ ((rowA & 6) << 3);
    int growA = m0 + rowA; if (growA > NN-1) growA = NN-1;
    const char* a0base = (const char*)(A0 + (size_t)growA*lda0) + swzA;
    const char* a1base = (const char*)(A1 + (size_t)growA*lda1) + swzA;
    const char* bbase[4];
    #pragma unroll
    for (int c = 0; c < 4; ++c){
        int p = (w*4 + c)*1024 + l*16;
        int n = p >> 6;
        int swz = (p & 63) ^ ((n & 6) << 3);
        bbase[c] = (const char*)(Bt + (size_t)n*KTOT) + swz;
    }

    f32x4 acc[4][4] = {};

    auto stage = [&](int s, int buf){
        const int k0 = s * BK;
        char* dst = smem + buf*TILEB;
        const char* gA = (k0 < K0) ? (a0base + (size_t)k0*2)
                                   : (a1base + (size_t)(k0 - K0)*2);
        gload16(gA, dst + w*1024);
        #pragma unroll
        for (int c = 0; c < 4; ++c)
            gload16(bbase[c] + (size_t)k0*2, dst + ABYTES + (w*4 + c)*1024);
    };

    const int nsteps = KTOT / BK;
    stage(0, 0);
    for (int s = 0; s < nsteps; ++s){
        const int cur = s & 1;
        if (s + 1 < nsteps){
            stage(s + 1, cur ^ 1);
            asm volatile("s_waitcnt vmcnt(5)" ::: "memory");
        } else {
            asm volatile("s_waitcnt vmcnt(0)" ::: "memory");
        }
        __builtin_amdgcn_s_barrier();
        __builtin_amdgcn_sched_barrier(0);

        const char* As = smem + cur*TILEB;
        const char* Bs = As + ABYTES;
        const int kb = lg * 16;
        const int sw = (lr & 6) << 3;
        bf16x8 af[4], bfr[4];
        #pragma unroll
        for (int m = 0; m < 4; ++m){
            int r = m*16 + lr;
            af[m] = *(const bf16x8*)(As + r*64 + (kb ^ sw));
        }
        #pragma unroll
        for (int n = 0; n < 4; ++n){
            int r = w*64 + n*16 + lr;
            bfr[n] = *(const bf16x8*)(Bs + r*64 + (kb ^ sw));
        }
        #pragma unroll
        for (int m = 0; m < 4; ++m)
            #pragma unroll
            for (int n = 0; n < 4; ++n)
                acc[m][n] = __builtin_amdgcn_mfma_f32_16x16x32_bf16(af[m], bfr[n], acc[m][n], 0, 0, 0);

        asm volatile("s_waitcnt lgkmcnt(0)" ::: "memory");
        __builtin_amdgcn_s_barrier();
    }

    // ---- epilogue: C/D layout col=lane&15, row=(lane>>4)*4+reg [m89-verified] ----
    float bcol[4], gcol[4], becol[4];
    #pragma unroll
    for (int n = 0; n < 4; ++n){
        int c = w*64 + n*16 + lr;
        bcol[n] = bias[c];
        if (EPI >= 1){ gcol[n] = gamma[c]; becol[n] = beta[c]; }
    }

    float* red  = (float*)smem;        // [wave][64 rows][2] for LN sums (2 KB)
    float* red2 = red + 512;           // [wave][64 rows]    for row max (1 KB)
    float pmx[4][4];

    if (EPI == 0){
        #pragma unroll
        for (int m = 0; m < 4; ++m)
        #pragma unroll
        for (int reg = 0; reg < 4; ++reg){
            int R = m*16 + lg*4 + reg;
            int grow = m0 + R;
            float mx = 0.f;
            #pragma unroll
            for (int n = 0; n < 4; ++n){
                int c = w*64 + n*16 + lr;
                float v = fmaxf(acc[m][n][reg] + bcol[n], 0.f);
                acc[m][n][reg] = v;
                mx = fmaxf(mx, v);
                if (grow < NN) outb[(size_t)grow*HH + c] = f2bf(v);
            }
            pmx[m][reg] = mx;
        }
    } else {
        float sm[4][4], sq[4][4];
        #pragma unroll
        for (int m = 0; m < 4; ++m)
        #pragma unroll
        for (int reg = 0; reg < 4; ++reg){
            float s = 0.f, q = 0.f;
            #pragma unroll
            for (int n = 0; n < 4; ++n){
                float v = acc[m][n][reg] + bcol[n];
                acc[m][n][reg] = v;
                s += v; q += v*v;
            }
            sm[m][reg] = s; sq[m][reg] = q;
        }
        #pragma unroll
        for (int mask = 1; mask <= 8; mask <<= 1){
            #pragma unroll
            for (int m = 0; m < 4; ++m)
            #pragma unroll
            for (int reg = 0; reg < 4; ++reg){
                sm[m][reg] += __shfl_xor(sm[m][reg], mask);
                sq[m][reg] += __shfl_xor(sq[m][reg], mask);
            }
        }
        __syncthreads();
        if (lr == 0){
            #pragma unroll
            for (int m = 0; m < 4; ++m)
            #pragma unroll
            for (int reg = 0; reg < 4; ++reg){
                int R = m*16 + lg*4 + reg;
                red[(w*64 + R)*2 + 0] = sm[m][reg];
                red[(w*64 + R)*2 + 1] = sq[m][reg];
            }
        }
        __syncthreads();
        #pragma unroll
        for (int m = 0; m < 4; ++m)
        #pragma unroll
        for (int reg = 0; reg < 4; ++reg){
            int R = m*16 + lg*4 + reg;
            float S = 0.f, Q = 0.f;
            #pragma unroll
            for (int ww = 0; ww < 4; ++ww){
                S += red[(ww*64 + R)*2 + 0];
                Q += red[(ww*64 + R)*2 + 1];
            }
            float mean = S * (1.0f/HH);
            float var  = Q * (1.0f/HH) - mean*mean;
            float inv  = rsqrtf(var + 1e-5f);
            int grow = m0 + R;
            float mx = 0.f;
            #pragma unroll
            for (int n = 0; n < 4; ++n){
                int c = w*64 + n*16 + lr;
                float o = fmaxf((acc[m][n][reg] - mean)*inv*gcol[n] + becol[n], 0.f)
                          + bf2f(resb[(size_t)grow*HH + c]);
                acc[m][n][reg] = o;
                mx = fmaxf(mx, o);
                if (grow < NN){
                    if (EPI == 1) outb[(size_t)grow*HH + c] = f2bf(o);
                    else          outf[(size_t)grow*HH + c] = o;
                }
            }
            pmx[m][reg] = mx;
        }
    }

    if (EPI <= 1){
        // row-max reduce -> u8 quantized mirror + per-row scale
        #pragma unroll
        for (int mask = 1; mask <= 8; mask <<= 1){
            #pragma unroll
            for (int m = 0; m < 4; ++m)
            #pragma unroll
            for (int reg = 0; reg < 4; ++reg)
                pmx[m][reg] = fmaxf(pmx[m][reg], __shfl_xor(pmx[m][reg], mask));
        }
        if (EPI == 0) __syncthreads();   // EPI1 already synced; EPI0 needs smem handoff
        if (lr == 0){
            #pragma unroll
            for (int m = 0; m < 4; ++m)
            #pragma unroll
            for (int reg = 0; reg < 4; ++reg){
                int R = m*16 + lg*4 + reg;
                red2[w*64 + R] = pmx[m][reg];
            }
        }
        __syncthreads();
        #pragma unroll
        for (int m = 0; m < 4; ++m)
        #pragma unroll
        for (int reg = 0; reg < 4; ++reg){
            int R = m*16 + lg*4 + reg;
            float rmax = fmaxf(fmaxf(red2[R], red2[64 + R]),
                               fmaxf(red2[128 + R], red2[192 + R]));
            float qinv = (rmax > 0.f) ? (255.0f / rmax) : 0.f;
            int grow = m0 + R;
            if (grow >= NN) continue;
            #pragma unroll
            for (int n = 0; n < 4; ++n){
                int c = w*64 + n*16 + lr;
                hu[(size_t)grow*HH + c] = (unsigned char)(acc[m][n][reg]*qinv + 0.5f);
            }
            if (w == 0 && lr == 0) scl[grow] = rmax * (1.0f/255.0f);
        }
    }
}

// ---------------- host ----------------
extern "C" void kernel_launch(void* const* d_in, const int* in_sizes, int n_in,
                              void* d_out, int out_size, void* d_ws, size_t ws_size,
                              hipStream_t stream) {
    const float* x     = (const float*)d_in[0];
    const int*   ei    = (const int*)d_in[1];
    const int*   srcI  = ei;
    const int*   dstI  = ei + EE;
    const float* Wp    = (const float*)d_in[2];
    const float* bp    = (const float*)d_in[3];
    const float* Wl    = (const float*)d_in[4];
    const float* bl    = (const float*)d_in[5];
    const float* Wr    = (const float*)d_in[6];
    const float* gamma = (const float*)d_in[7];
    const float* beta  = (const float*)d_in[8];
    float* out = (float*)d_out;

    char* ws = (char*)d_ws;
    size_t off_b = 0;
    auto alloc = [&](size_t bytes) -> char* {
        char* p = ws + off_b;
        off_b = (off_b + bytes + 255) & ~(size_t)255;
        return p;
    };
    unsigned short* Hb0  = (unsigned short*)alloc((size_t)NN*HH*2);
    unsigned short* Hb1  = (unsigned short*)alloc((size_t)NN*HH*2);
    unsigned short* AGGb = (unsigned short*)alloc((size_t)NN*HH*2);
    unsigned char*  Hu0  = (unsigned char*)alloc((size_t)NN*HH);
    unsigned char*  Hu1  = (unsigned char*)alloc((size_t)NN*HH);
    float* Scl0 = (float*)alloc((size_t)NN*4);
    float* Scl1 = (float*)alloc((size_t)NN*4);
    unsigned short* Xb = (unsigned short*)alloc((size_t)NN*FIN*2);
    int*   csr  = (int*)alloc((size_t)EE*4);
    int*   deg  = (int*)alloc((size_t)NN*4);
    int*   offs = (int*)alloc((size_t)NN*4);
    int*   pos  = (int*)alloc((size_t)NN*4);
    float* invd = (float*)alloc((size_t)NN*4);
    int*   bsum = (int*)alloc(64*4);
    unsigned short* Wpb = (unsigned short*)alloc((size_t)HH*FIN*2);
    unsigned short* Wb  = (unsigned short*)alloc((size_t)NL*HH*2*HH*2);
    (void)ws_size; (void)in_sizes; (void)n_in; (void)out_size;

    const int NB = (NN + 1023)/1024;

    k_zero_i32<<<(NN + 255)/256, 256, 0, stream>>>(deg, NN);
    k_count_deg<<<(EE + 255)/256, 256, 0, stream>>>(dstI, deg);
    k_block_sum<<<NB, 1024, 0, stream>>>(deg, bsum);
    k_scan_bsum<<<1, 1, 0, stream>>>(bsum, NB);
    k_make_off<<<NB, 1024, 0, stream>>>(deg, bsum, offs, pos, invd);
    k_build_csr<<<(EE + 255)/256, 256, 0, stream>>>(srcI, dstI, pos, csr);

    k_prep<<<(NX + NWP + NWC + 255)/256, 256, 0, stream>>>(x, Wp, Wl, Wr, Xb, Wpb, Wb);

    const int GB = (NN + BM - 1)/BM;  // 782

    // input projection + ReLU -> Hb0 (bf16) + Hu0/Scl0 (u8)
    k_gemm_mfma<0><<<GB, 256, 0, stream>>>(Xb, FIN, Xb, FIN, Wpb, bp,
                                           nullptr, nullptr, nullptr,
                                           nullptr, Hb0, Hu0, Scl0,
                                           FIN, FIN);

    unsigned short* hin = Hb0;
    unsigned char*  huin = Hu0;
    float*          sclin = Scl0;
    for (int lyr = 0; lyr < NL; ++lyr){
        k_aggregate_u8<<<(NN + 3)/4, 256, 0, stream>>>(huin, sclin, csr, offs, deg,
                                                       invd, AGGb);
        unsigned short* hout  = (hin == Hb0) ? Hb1 : Hb0;
        unsigned char*  huout = (huin == Hu0) ? Hu1 : Hu0;
        float*          sclout= (sclin == Scl0) ? Scl1 : Scl0;
        const unsigned short* Wbt = Wb + (size_t)lyr*HH*2*HH;
        if (lyr < NL-1)
            k_gemm_mfma<1><<<GB, 256, 0, stream>>>(AGGb, HH, hin, HH, Wbt, bl + lyr*HH,
                                                   gamma + lyr*HH, beta + lyr*HH, hin,
                                                   nullptr, hout, huout, sclout,
                                                   HH, 2*HH);
        else
            k_gemm_mfma<2><<<GB, 256, 0, stream>>>(AGGb, HH, hin, HH, Wbt, bl + lyr*HH,
                                                   gamma + lyr*HH, beta + lyr*HH, hin,
                                                   out, nullptr, nullptr, nullptr,
                                                   HH, 2*HH);
        hin = hout; huin = huout; sclin = sclout;
    }
}

// Round 6
// 376.323 us; speedup vs baseline: 1.5150x; 1.0743x over previous
//
#include <hip/hip_runtime.h>

#define NN 50000
#define EE 800000
#define FIN 128
#define HH 256
#define NL 3

#define BM 64
#define BK 32
#define ABYTES (BM*BK*2)          // 4096
#define BBYTES (HH*BK*2)          // 16384
#define TILEB  (ABYTES + BBYTES)  // 20480

typedef __bf16 bf16x8 __attribute__((ext_vector_type(8)));
typedef float  f32x4  __attribute__((ext_vector_type(4)));
typedef unsigned short u16x8 __attribute__((ext_vector_type(8)));

__device__ __forceinline__ float bf2f(unsigned short u){
    union { unsigned int i; float f; } v; v.i = ((unsigned int)u) << 16; return v.f;
}
__device__ __forceinline__ unsigned short f2bf(float f){
    union { float f; unsigned int i; } v; v.f = f;
    unsigned int r = v.i + 0x7FFF + ((v.i >> 16) & 1);  // RNE
    return (unsigned short)(r >> 16);
}
__device__ __forceinline__ void gload16(const void* g, void* s){
    __builtin_amdgcn_global_load_lds(
        (const __attribute__((address_space(1))) void*)g,
        (__attribute__((address_space(3))) void*)s, 16, 0, 0);
}

// ---------------- CSR build ----------------
__global__ void k_zero_i32(int* __restrict__ p, int n){
    int i = blockIdx.x*256 + threadIdx.x;
    if (i < n) p[i] = 0;
}
__global__ void k_count_deg(const int* __restrict__ dst, int* __restrict__ deg){
    int i = blockIdx.x*256 + threadIdx.x;
    if (i < EE) atomicAdd(&deg[dst[i]], 1);
}
__global__ void k_block_sum(const int* __restrict__ deg, int* __restrict__ bsum){
    __shared__ int s[1024];
    int i = blockIdx.x*1024 + threadIdx.x;
    s[threadIdx.x] = (i < NN) ? deg[i] : 0;
    __syncthreads();
    for (int o = 512; o > 0; o >>= 1){
        if (threadIdx.x < o) s[threadIdx.x] += s[threadIdx.x + o];
        __syncthreads();
    }
    if (threadIdx.x == 0) bsum[blockIdx.x] = s[0];
}
__global__ void k_scan_bsum(int* __restrict__ bsum, int nb){
    if (threadIdx.x == 0 && blockIdx.x == 0){
        int run = 0;
        for (int i = 0; i < nb; ++i){ int v = bsum[i]; bsum[i] = run; run += v; }
    }
}
__global__ void k_make_off(const int* __restrict__ deg, const int* __restrict__ bsum,
                           int* __restrict__ off, int* __restrict__ pos,
                           float* __restrict__ invd){
    __shared__ int s[1024];
    int t = threadIdx.x;
    int i = blockIdx.x*1024 + t;
    int v = (i < NN) ? deg[i] : 0;
    s[t] = v; __syncthreads();
    for (int o = 1; o < 1024; o <<= 1){
        int add = (t >= o) ? s[t - o] : 0;
        __syncthreads();
        s[t] += add;
        __syncthreads();
    }
    if (i < NN){
        int excl = s[t] - v + bsum[blockIdx.x];
        off[i] = excl; pos[i] = excl;
        invd[i] = 1.0f / fmaxf((float)v, 1.0f);
    }
}
__global__ void k_build_csr(const int* __restrict__ src, const int* __restrict__ dst,
                            int* __restrict__ pos, int* __restrict__ csr){
    int i = blockIdx.x*256 + threadIdx.x;
    if (i < EE){
        int p = atomicAdd(&pos[dst[i]], 1);
        csr[p] = src[i];
    }
}

// ---------------- fused prep: cast x, Wp, and [Wl|Wr] concat to bf16 ----------------
#define NX  (NN*FIN/4)
#define NWP (HH*FIN/4)
#define NWC (NL*HH*2*HH/4)
__global__ void k_prep(const float* __restrict__ x, const float* __restrict__ Wp,
                       const float* __restrict__ Wl, const float* __restrict__ Wr,
                       unsigned short* __restrict__ Xb, unsigned short* __restrict__ Wpb,
                       unsigned short* __restrict__ Wb){
    int i = blockIdx.x*256 + threadIdx.x;
    if (i < NX){
        float4 v = *(const float4*)&x[i*4];
        ushort4 o; o.x=f2bf(v.x); o.y=f2bf(v.y); o.z=f2bf(v.z); o.w=f2bf(v.w);
        *(ushort4*)&Xb[i*4] = o;
        return;
    }
    int j = i - NX;
    if (j < NWP){
        float4 v = *(const float4*)&Wp[j*4];
        ushort4 o; o.x=f2bf(v.x); o.y=f2bf(v.y); o.z=f2bf(v.z); o.w=f2bf(v.w);
        *(ushort4*)&Wpb[j*4] = o;
        return;
    }
    int k4 = j - NWP;
    if (k4 < NWC){
        int base = k4*4;
        int kk  = base & 511;
        int n   = (base >> 9) & (HH-1);
        int lyr = base >> 17;
        const float* srcp = (kk < HH) ? &Wl[((size_t)lyr*HH + n)*HH + kk]
                                      : &Wr[((size_t)lyr*HH + n)*HH + (kk - HH)];
        float4 v = *(const float4*)srcp;
        ushort4 o; o.x=f2bf(v.x); o.y=f2bf(v.y); o.z=f2bf(v.z); o.w=f2bf(v.w);
        *(ushort4*)&Wb[base] = o;
    }
}

// ---------------- aggregation: u8 rows (256B), 16 lanes/row, 4 rows/instr ----------------
__device__ __forceinline__ void accum16(float* a, uint4 v, float c){
    const unsigned int w0 = v.x, w1 = v.y, w2 = v.z, w3 = v.w;
    #pragma unroll
    for (int b = 0; b < 4; ++b){
        a[b]    += c * (float)((w0 >> (8*b)) & 0xFF);
        a[4+b]  += c * (float)((w1 >> (8*b)) & 0xFF);
        a[8+b]  += c * (float)((w2 >> (8*b)) & 0xFF);
        a[12+b] += c * (float)((w3 >> (8*b)) & 0xFF);
    }
}

__global__ __launch_bounds__(256) void k_aggregate_u8(
    const unsigned char* __restrict__ hu, const float* __restrict__ scl,
    const int* __restrict__ csr, const int* __restrict__ off,
    const int* __restrict__ deg, const float* __restrict__ invd,
    unsigned short* __restrict__ aggb)
{
    const int wave = threadIdx.x >> 6, lane = threadIdx.x & 63;
    const int node = blockIdx.x*4 + wave;
    if (node >= NN) return;
    const int o = off[node], d = deg[node];
    const int grp = lane >> 4;
    const int fl  = lane & 15;

    float acc[16] = {};
    int j = 0;
    for (; j + 16 <= d; j += 16){
        int s0 = csr[o + j      + grp];
        int s1 = csr[o + j + 4  + grp];
        int s2 = csr[o + j + 8  + grp];
        int s3 = csr[o + j + 12 + grp];
        float c0 = scl[s0], c1 = scl[s1], c2 = scl[s2], c3 = scl[s3];
        uint4 v0 = *(const uint4*)&hu[(size_t)s0*HH + fl*16];
        uint4 v1 = *(const uint4*)&hu[(size_t)s1*HH + fl*16];
        uint4 v2 = *(const uint4*)&hu[(size_t)s2*HH + fl*16];
        uint4 v3 = *(const uint4*)&hu[(size_t)s3*HH + fl*16];
        accum16(acc, v0, c0); accum16(acc, v1, c1);
        accum16(acc, v2, c2); accum16(acc, v3, c3);
    }
    for (; j + 8 <= d; j += 8){
        int s0 = csr[o + j     + grp];
        int s1 = csr[o + j + 4 + grp];
        float c0 = scl[s0], c1 = scl[s1];
        uint4 v0 = *(const uint4*)&hu[(size_t)s0*HH + fl*16];
        uint4 v1 = *(const uint4*)&hu[(size_t)s1*HH + fl*16];
        accum16(acc, v0, c0); accum16(acc, v1, c1);
    }
    for (; j < d; j += 4){
        int idx = j + grp;
        int s0 = 0; float c0 = 0.f;
        if (idx < d){ s0 = csr[o + idx]; c0 = scl[s0]; }
        uint4 v0 = *(const uint4*)&hu[(size_t)s0*HH + fl*16];
        accum16(acc, v0, c0);
    }
    #pragma unroll
    for (int k = 0; k < 16; ++k){
        acc[k] += __shfl_xor(acc[k], 16);
        acc[k] += __shfl_xor(acc[k], 32);
    }
    if (grp == 0){
        float id = invd[node];
        u16x8 r0, r1;
        #pragma unroll
        for (int k = 0; k < 8; ++k){
            r0[k] = f2bf(acc[k]*id);
            r1[k] = f2bf(acc[8+k]*id);
        }
        *(u16x8*)&aggb[(size_t)node*HH + fl*16]     = r0;
        *(u16x8*)&aggb[(size_t)node*HH + fl*16 + 8] = r1;
    }
}

// ---------------- MFMA GEMM, BM=64 x BN=256, 8 waves (2M x 4N), fused epilogue ----------------
// EPI 0: h = relu(C+bias)            -> outb bf16 + hu u8 + scl
// EPI 1: h = relu(LN(C+bias)) + resb -> outb bf16 + hu u8 + scl
// EPI 2: h = relu(LN(C+bias)) + resb -> outf f32 (final)
template<int EPI>
__global__ __launch_bounds__(512) void k_gemm_mfma(
    const unsigned short* __restrict__ A0, int lda0,
    const unsigned short* __restrict__ A1, int lda1,
    const unsigned short* __restrict__ Bt,
    const float* __restrict__ bias,
    const float* __restrict__ gamma, const float* __restrict__ beta,
    const unsigned short* __restrict__ resb,
    float* __restrict__ outf, unsigned short* __restrict__ outb,
    unsigned char* __restrict__ hu, float* __restrict__ scl,
    int K0, int KTOT)
{
    __shared__ char smem[2*TILEB];   // 40 KB
    const int t  = threadIdx.x;
    const int w  = t >> 6, l = t & 63;
    const int lr = l & 15, lg = l >> 4;
    const int wm = w >> 2, wn = w & 3;       // 2 x 4 wave grid
    const int m0 = blockIdx.x * BM;

    // ---- staging setup: B = 1024 16B-units (2/thread), A = 256 units (waves 0-3) ----
    const char* bsrc[2]; int bdst[2];
    #pragma unroll
    for (int i = 0; i < 2; ++i){
        int u   = t + i*512;
        int row = u >> 2;
        int swz = ((u & 3)*16) ^ ((row & 6) << 3);
        bsrc[i] = (const char*)(Bt + (size_t)row*KTOT) + swz;
        bdst[i] = ABYTES + u*16;
    }
    const int ua   = t & 255;
    const int rowA = ua >> 2;
    const int swzA = ((ua & 3)*16) ^ ((rowA & 6) << 3);
    int growA = m0 + rowA; if (growA > NN-1) growA = NN-1;
    const char* a0src = (const char*)(A0 + (size_t)growA*lda0) + swzA;
    const char* a1src = (const char*)(A1 + (size_t)growA*lda1) + swzA;
    const int adst = ua*16;
    const bool hasA = (w < 4);   // wave-uniform

    f32x4 acc[2][4] = {};

    auto stage = [&](int s, int buf){
        const int k0 = s * BK;
        char* dst = smem + buf*TILEB;
        if (hasA){
            const char* g = (k0 < K0) ? (a0src + (size_t)k0*2)
                                      : (a1src + (size_t)(k0 - K0)*2);
            gload16(g, dst + adst);
        }
        gload16(bsrc[0] + (size_t)k0*2, dst + bdst[0]);
        gload16(bsrc[1] + (size_t)k0*2, dst + bdst[1]);
    };

    const int nsteps = KTOT / BK;
    stage(0, 0);
    for (int s = 0; s < nsteps; ++s){
        const int cur = s & 1;
        if (s + 1 < nsteps){
            stage(s + 1, cur ^ 1);
            if (hasA) { asm volatile("s_waitcnt vmcnt(3)" ::: "memory"); }
            else      { asm volatile("s_waitcnt vmcnt(2)" ::: "memory"); }
        } else {
            asm volatile("s_waitcnt vmcnt(0)" ::: "memory");
        }
        __builtin_amdgcn_s_barrier();
        __builtin_amdgcn_sched_barrier(0);

        const char* As = smem + cur*TILEB;
        const char* Bs = As + ABYTES;
        const int kb = lg * 16;
        const int sw = (lr & 6) << 3;
        bf16x8 af[2], bfr[4];
        #pragma unroll
        for (int m = 0; m < 2; ++m){
            int r = wm*32 + m*16 + lr;
            af[m] = *(const bf16x8*)(As + r*64 + (kb ^ sw));
        }
        #pragma unroll
        for (int n = 0; n < 4; ++n){
            int r = wn*64 + n*16 + lr;
            bfr[n] = *(const bf16x8*)(Bs + r*64 + (kb ^ sw));
        }
        #pragma unroll
        for (int m = 0; m < 2; ++m)
            #pragma unroll
            for (int n = 0; n < 4; ++n)
                acc[m][n] = __builtin_amdgcn_mfma_f32_16x16x32_bf16(af[m], bfr[n], acc[m][n], 0, 0, 0);

        asm volatile("s_waitcnt lgkmcnt(0)" ::: "memory");
        __builtin_amdgcn_s_barrier();
    }

    // ---- epilogue: C/D layout col=lane&15, row=(lane>>4)*4+reg [m89-verified] ----
    float bcol[4], gcol[4], becol[4];
    #pragma unroll
    for (int n = 0; n < 4; ++n){
        int c = wn*64 + n*16 + lr;
        bcol[n] = bias[c];
        if (EPI >= 1){ gcol[n] = gamma[c]; becol[n] = beta[c]; }
    }

    float* red  = (float*)smem;        // [4 wn][64 R][2]  LN partials (2 KB)
    float* red2 = red + 512;           // [4 wn][64 R]     row max (1 KB)
    float pmx[2][4];

    if (EPI == 0){
        #pragma unroll
        for (int m = 0; m < 2; ++m)
        #pragma unroll
        for (int reg = 0; reg < 4; ++reg){
            int R = wm*32 + m*16 + lg*4 + reg;
            int grow = m0 + R;
            float mx = 0.f;
            #pragma unroll
            for (int n = 0; n < 4; ++n){
                int c = wn*64 + n*16 + lr;
                float v = fmaxf(acc[m][n][reg] + bcol[n], 0.f);
                acc[m][n][reg] = v;
                mx = fmaxf(mx, v);
                if (grow < NN) outb[(size_t)grow*HH + c] = f2bf(v);
            }
            pmx[m][reg] = mx;
        }
    } else {
        float sm[2][4], sq[2][4];
        #pragma unroll
        for (int m = 0; m < 2; ++m)
        #pragma unroll
        for (int reg = 0; reg < 4; ++reg){
            float s = 0.f, q = 0.f;
            #pragma unroll
            for (int n = 0; n < 4; ++n){
                float v = acc[m][n][reg] + bcol[n];
                acc[m][n][reg] = v;
                s += v; q += v*v;
            }
            sm[m][reg] = s; sq[m][reg] = q;
        }
        #pragma unroll
        for (int mask = 1; mask <= 8; mask <<= 1){
            #pragma unroll
            for (int m = 0; m < 2; ++m)
            #pragma unroll
            for (int reg = 0; reg < 4; ++reg){
                sm[m][reg] += __shfl_xor(sm[m][reg], mask);
                sq[m][reg] += __shfl_xor(sq[m][reg], mask);
            }
        }
        if (lr == 0){
            #pragma unroll
            for (int m = 0; m < 2; ++m)
            #pragma unroll
            for (int reg = 0; reg < 4; ++reg){
                int R = wm*32 + m*16 + lg*4 + reg;
                red[(wn*64 + R)*2 + 0] = sm[m][reg];
                red[(wn*64 + R)*2 + 1] = sq[m][reg];
            }
        }
        __syncthreads();
        #pragma unroll
        for (int m = 0; m < 2; ++m)
        #pragma unroll
        for (int reg = 0; reg < 4; ++reg){
            int R = wm*32 + m*16 + lg*4 + reg;
            float S = 0.f, Q = 0.f;
            #pragma unroll
            for (int ww = 0; ww < 4; ++ww){
                S += red[(ww*64 + R)*2 + 0];
                Q += red[(ww*64 + R)*2 + 1];
            }
            float mean = S * (1.0f/HH);
            float var  = Q * (1.0f/HH) - mean*mean;
            float inv  = rsqrtf(var + 1e-5f);
            int grow = m0 + R;
            int growc = (grow > NN-1) ? NN-1 : grow;   // clamp reads
            float mx = 0.f;
            #pragma unroll
            for (int n = 0; n < 4; ++n){
                int c = wn*64 + n*16 + lr;
                float o = fmaxf((acc[m][n][reg] - mean)*inv*gcol[n] + becol[n], 0.f)
                          + bf2f(resb[(size_t)growc*HH + c]);
                acc[m][n][reg] = o;
                mx = fmaxf(mx, o);
                if (grow < NN){
                    if (EPI == 1) outb[(size_t)grow*HH + c] = f2bf(o);
                    else          outf[(size_t)grow*HH + c] = o;
                }
            }
            pmx[m][reg] = mx;
        }
    }

    if (EPI <= 1){
        #pragma unroll
        for (int mask = 1; mask <= 8; mask <<= 1){
            #pragma unroll
            for (int m = 0; m < 2; ++m)
            #pragma unroll
            for (int reg = 0; reg < 4; ++reg)
                pmx[m][reg] = fmaxf(pmx[m][reg], __shfl_xor(pmx[m][reg], mask));
        }
        if (lr == 0){
            #pragma unroll
            for (int m = 0; m < 2; ++m)
            #pragma unroll
            for (int reg = 0; reg < 4; ++reg){
                int R = wm*32 + m*16 + lg*4 + reg;
                red2[wn*64 + R] = pmx[m][reg];
            }
        }
        __syncthreads();
        #pragma unroll
        for (int m = 0; m < 2; ++m)
        #pragma unroll
        for (int reg = 0; reg < 4; ++reg){
            int R = wm*32 + m*16 + lg*4 + reg;
            float rmax = fmaxf(fmaxf(red2[R], red2[64 + R]),
                               fmaxf(red2[128 + R], red2[192 + R]));
            float qinv = (rmax > 0.f) ? (255.0f / rmax) : 0.f;
            int grow = m0 + R;
            if (grow >= NN) continue;
            #pragma unroll
            for (int n = 0; n < 4; ++n){
                int c = wn*64 + n*16 + lr;
                hu[(size_t)grow*HH + c] = (unsigned char)(acc[m][n][reg]*qinv + 0.5f);
            }
            if (wn == 0 && lr == 0) scl[grow] = rmax * (1.0f/255.0f);
        }
    }
}

// ---------------- host ----------------
extern "C" void kernel_launch(void* const* d_in, const int* in_sizes, int n_in,
                              void* d_out, int out_size, void* d_ws, size_t ws_size,
                              hipStream_t stream) {
    const float* x     = (const float*)d_in[0];
    const int*   ei    = (const int*)d_in[1];
    const int*   srcI  = ei;
    const int*   dstI  = ei + EE;
    const float* Wp    = (const float*)d_in[2];
    const float* bp    = (const float*)d_in[3];
    const float* Wl    = (const float*)d_in[4];
    const float* bl    = (const float*)d_in[5];
    const float* Wr    = (const float*)d_in[6];
    const float* gamma = (const float*)d_in[7];
    const float* beta  = (const float*)d_in[8];
    float* out = (float*)d_out;

    char* ws = (char*)d_ws;
    size_t off_b = 0;
    auto alloc = [&](size_t bytes) -> char* {
        char* p = ws + off_b;
        off_b = (off_b + bytes + 255) & ~(size_t)255;
        return p;
    };
    unsigned short* Hb0  = (unsigned short*)alloc((size_t)NN*HH*2);
    unsigned short* Hb1  = (unsigned short*)alloc((size_t)NN*HH*2);
    unsigned short* AGGb = (unsigned short*)alloc((size_t)NN*HH*2);
    unsigned char*  Hu0  = (unsigned char*)alloc((size_t)NN*HH);
    unsigned char*  Hu1  = (unsigned char*)alloc((size_t)NN*HH);
    float* Scl0 = (float*)alloc((size_t)NN*4);
    float* Scl1 = (float*)alloc((size_t)NN*4);
    unsigned short* Xb = (unsigned short*)alloc((size_t)NN*FIN*2);
    int*   csr  = (int*)alloc((size_t)EE*4);
    int*   deg  = (int*)alloc((size_t)NN*4);
    int*   offs = (int*)alloc((size_t)NN*4);
    int*   pos  = (int*)alloc((size_t)NN*4);
    float* invd = (float*)alloc((size_t)NN*4);
    int*   bsum = (int*)alloc(64*4);
    unsigned short* Wpb = (unsigned short*)alloc((size_t)HH*FIN*2);
    unsigned short* Wb  = (unsigned short*)alloc((size_t)NL*HH*2*HH*2);
    (void)ws_size; (void)in_sizes; (void)n_in; (void)out_size;

    const int NB = (NN + 1023)/1024;

    k_zero_i32<<<(NN + 255)/256, 256, 0, stream>>>(deg, NN);
    k_count_deg<<<(EE + 255)/256, 256, 0, stream>>>(dstI, deg);
    k_block_sum<<<NB, 1024, 0, stream>>>(deg, bsum);
    k_scan_bsum<<<1, 1, 0, stream>>>(bsum, NB);
    k_make_off<<<NB, 1024, 0, stream>>>(deg, bsum, offs, pos, invd);
    k_build_csr<<<(EE + 255)/256, 256, 0, stream>>>(srcI, dstI, pos, csr);

    k_prep<<<(NX + NWP + NWC + 255)/256, 256, 0, stream>>>(x, Wp, Wl, Wr, Xb, Wpb, Wb);

    const int GB = (NN + BM - 1)/BM;  // 782

    // input projection + ReLU -> Hb0 (bf16) + Hu0/Scl0 (u8)
    k_gemm_mfma<0><<<GB, 512, 0, stream>>>(Xb, FIN, Xb, FIN, Wpb, bp,
                                           nullptr, nullptr, nullptr,
                                           nullptr, Hb0, Hu0, Scl0,
                                           FIN, FIN);

    unsigned short* hin = Hb0;
    unsigned char*  huin = Hu0;
    float*          sclin = Scl0;
    for (int lyr = 0; lyr < NL; ++lyr){
        k_aggregate_u8<<<(NN + 3)/4, 256, 0, stream>>>(huin, sclin, csr, offs, deg,
                                                       invd, AGGb);
        unsigned short* hout  = (hin == Hb0) ? Hb1 : Hb0;
        unsigned char*  huout = (huin == Hu0) ? Hu1 : Hu0;
        float*          sclout= (sclin == Scl0) ? Scl1 : Scl0;
        const unsigned short* Wbt = Wb + (size_t)lyr*HH*2*HH;
        if (lyr < NL-1)
            k_gemm_mfma<1><<<GB, 512, 0, stream>>>(AGGb, HH, hin, HH, Wbt, bl + lyr*HH,
                                                   gamma + lyr*HH, beta + lyr*HH, hin,
                                                   nullptr, hout, huout, sclout,
                                                   HH, 2*HH);
        else
            k_gemm_mfma<2><<<GB, 512, 0, stream>>>(AGGb, HH, hin, HH, Wbt, bl + lyr*HH,
                                                   gamma + lyr*HH, beta + lyr*HH, hin,
                                                   out, nullptr, nullptr, nullptr,
                                                   HH, 2*HH);
        hin = hout; huin = huout; sclin = sclout;
    }
}